// Round 7
// baseline (603.208 us; speedup 1.0000x reference)
//
#include <hip/hip_runtime.h>
#include <hip/hip_bf16.h>

#define B_   16
#define T_   2048
#define E_   1024
#define S_   2000
#define HID_ 150
#define GI_  3072

typedef __attribute__((ext_vector_type(8))) short short8;   // 8 bf16 (4 VGPRs)
typedef __attribute__((ext_vector_type(4))) float f32x4;

constexpr int NPAD  = 160;   // HID padded to 10 MFMA col-tiles
constexpr int LSTR  = 168;   // hl row stride (bf16): 336 B
constexpr int MROWS = 32;    // rows per MLP block (4 waves)

__device__ inline short8 pack8(float4 a, float4 b) {
    union { __hip_bfloat162 h[4]; short8 s; } u;
    u.h[0] = __float22bfloat162_rn(make_float2(a.x, a.y));
    u.h[1] = __float22bfloat162_rn(make_float2(a.z, a.w));
    u.h[2] = __float22bfloat162_rn(make_float2(b.x, b.y));
    u.h[3] = __float22bfloat162_rn(make_float2(b.z, b.w));
    return u.s;
}

// W [K x 150] f32  ->  Wt [160][DSTK] bf16, zero-padded (n>=150 or k>=SRCK)
template<int SRCK, int DSTK>
__global__ __launch_bounds__(256)
void transpose_w(const float* __restrict__ src, __hip_bfloat16* __restrict__ dst) {
    int i = blockIdx.x * 256 + threadIdx.x;      // i = n*DSTK + k
    if (i >= NPAD * DSTK) return;
    int n = i / DSTK, k = i - n * DSTK;
    float v = (n < HID_ && k < SRCK) ? src[(long long)k * HID_ + n] : 0.f;
    dst[i] = __float2bfloat16(v);
}

// Full MLP: K1 -> 150 (relu) -> 150 (relu) -> 1, MROWS rows/block, 4 waves.
// Wave w: rows [(w>>1)*16,+16), cols [(w&1)*80,+80).
// Stage 1: direct global loads, explicit 2-deep register pipeline (no barriers).
template<int K1>
__global__
void mlp_mfma(const float* __restrict__ xin,
              const __hip_bfloat16* __restrict__ Wt1, const float* __restrict__ b1,
              const __hip_bfloat16* __restrict__ Wt2, const float* __restrict__ b2,
              const float* __restrict__ W3, const float* __restrict__ b3,
              float* __restrict__ outp)
{
    __shared__ __hip_bfloat16 hl[MROWS * LSTR];

    const int tid  = threadIdx.x;
    const int lane = tid & 63;
    const int w    = tid >> 6;          // wave 0..3
    const int rg   = w >> 1;            // row group (16 rows)
    const int cg   = w & 1;             // col group (80 cols)
    const int lr   = lane & 15;
    const int hi   = lane >> 4;         // 0..3
    const int lk   = hi * 8;

    const long long row0 = (long long)blockIdx.x * MROWS;

    // ---------------- stage 1: K1 -> 160 (MFMA, 2-deep reg pipeline) --------
    f32x4 acc[5];
#pragma unroll
    for (int nt = 0; nt < 5; ++nt) acc[nt] = (f32x4){0.f, 0.f, 0.f, 0.f};

    const float* xrow = xin + (row0 + rg * 16 + lr) * K1;
    const __hip_bfloat16* brow[5];
#pragma unroll
    for (int nt = 0; nt < 5; ++nt)
        brow[nt] = Wt1 + (long long)(cg * 80 + nt * 16 + lr) * K1;

    constexpr int NS = K1 / 32;
    short8 bc[5];
    float4 ac0, ac1;
    {   // prologue: step 0
#pragma unroll
        for (int nt = 0; nt < 5; ++nt)
            bc[nt] = *(const short8*)(brow[nt] + lk);
        ac0 = *(const float4*)(xrow + lk);
        ac1 = *(const float4*)(xrow + lk + 4);
    }
#pragma unroll 2
    for (int s = 0; s < NS - 1; ++s) {
        const int kn = (s + 1) * 32 + lk;
        // issue next step's loads (consumed next iteration -> stay in flight)
        short8 bn[5];
#pragma unroll
        for (int nt = 0; nt < 5; ++nt)
            bn[nt] = *(const short8*)(brow[nt] + kn);
        float4 an0 = *(const float4*)(xrow + kn);
        float4 an1 = *(const float4*)(xrow + kn + 4);
        // compute current step
        short8 afr = pack8(ac0, ac1);
#pragma unroll
        for (int nt = 0; nt < 5; ++nt)
            acc[nt] = __builtin_amdgcn_mfma_f32_16x16x32_bf16(
                afr, bc[nt], acc[nt], 0, 0, 0);
        // rotate
#pragma unroll
        for (int nt = 0; nt < 5; ++nt) bc[nt] = bn[nt];
        ac0 = an0; ac1 = an1;
    }
    {   // epilogue: last step
        short8 afr = pack8(ac0, ac1);
#pragma unroll
        for (int nt = 0; nt < 5; ++nt)
            acc[nt] = __builtin_amdgcn_mfma_f32_16x16x32_bf16(
                afr, bc[nt], acc[nt], 0, 0, 0);
    }

    // bias + relu -> hl (bf16)
#pragma unroll
    for (int nt = 0; nt < 5; ++nt) {
        const int ch = cg * 80 + nt * 16 + lr;
        const float bb = (ch < HID_) ? b1[ch] : 0.f;
#pragma unroll
        for (int r = 0; r < 4; ++r) {
            const int row = rg * 16 + hi * 4 + r;
            float h = acc[nt][r] + bb;
            hl[row * LSTR + ch] = __float2bfloat16(h > 0.f ? h : 0.f);
        }
    }
    __syncthreads();

    // ---------------- stage 2: 160 -> 160 (MFMA, K=160) ----------------
    f32x4 acc2[5];
#pragma unroll
    for (int nt = 0; nt < 5; ++nt) acc2[nt] = (f32x4){0.f, 0.f, 0.f, 0.f};

#pragma unroll
    for (int ks = 0; ks < 5; ++ks) {
        const int k0 = ks * 32 + lk;
        short8 bfr[5];
#pragma unroll
        for (int nt = 0; nt < 5; ++nt)
            bfr[nt] = *(const short8*)(Wt2 + (cg * 80 + nt * 16 + lr) * NPAD + k0);
        short8 afr = *(const short8*)(&hl[(rg * 16 + lr) * LSTR + k0]);
#pragma unroll
        for (int nt = 0; nt < 5; ++nt)
            acc2[nt] = __builtin_amdgcn_mfma_f32_16x16x32_bf16(
                afr, bfr[nt], acc2[nt], 0, 0, 0);
    }
    __syncthreads();   // stage-2 reads done before overwrite

    // bias + relu -> hl (h2)
#pragma unroll
    for (int nt = 0; nt < 5; ++nt) {
        const int ch = cg * 80 + nt * 16 + lr;
        const float bb = (ch < HID_) ? b2[ch] : 0.f;
#pragma unroll
        for (int r = 0; r < 4; ++r) {
            const int row = rg * 16 + hi * 4 + r;
            float h = acc2[nt][r] + bb;
            hl[row * LSTR + ch] = __float2bfloat16(h > 0.f ? h : 0.f);
        }
    }
    __syncthreads();

    // ---------------- stage 3: 150 -> 1 (8 threads per row) ----------------
    {
        const int row = tid >> 3, oct = tid & 7;
        const int kb = oct * 19;
        const int ke = (kb + 19 > HID_) ? HID_ : kb + 19;
        float s = 0.f;
        for (int k = kb; k < ke; ++k)
            s += __bfloat162float(hl[row * LSTR + k]) * W3[k];
        s += __shfl_xor(s, 1);
        s += __shfl_xor(s, 2);
        s += __shfl_xor(s, 4);
        if (oct == 0) outp[row0 + row] = s + b3[0];
    }
}

// span_emb = [x[start], x[end], sum_{t=start..end} x[t]*attn[t]]  (f32 out)
__global__ __launch_bounds__(256)
void span_kernel(const float* __restrict__ x, const float* __restrict__ attn,
                 const int* __restrict__ starts, const int* __restrict__ lengths,
                 const int* __restrict__ nspans, float* __restrict__ out)
{
    const int blk = blockIdx.x;        // b*S + s
    const int b = blk / S_;
    const int s = blk - b * S_;
    const int tid = threadIdx.x;       // each thread: 4 consecutive elements
    float* orow = out + (long long)blk * (3 * E_);

    if (s >= nspans[b]) {
        float4 z = make_float4(0.f, 0.f, 0.f, 0.f);
        *(float4*)(orow + tid * 4)          = z;
        *(float4*)(orow + E_ + tid * 4)     = z;
        *(float4*)(orow + 2 * E_ + tid * 4) = z;
        return;
    }
    const int st = starts[blk];
    const int en = st + lengths[blk];   // inclusive end index, < T
    const float* xb = x + (long long)b * T_ * E_;

    float4 vs = *(const float4*)(xb + (long long)st * E_ + tid * 4);
    float4 ve = *(const float4*)(xb + (long long)en * E_ + tid * 4);
    *(float4*)(orow + tid * 4)      = vs;   // bit-exact g_start
    *(float4*)(orow + E_ + tid * 4) = ve;   // bit-exact g_end

    float4 a4 = make_float4(0.f, 0.f, 0.f, 0.f);
    const float* ab = attn + b * T_;
    for (int t = st; t <= en; ++t) {
        float a = ab[t];
        float4 v = *(const float4*)(xb + (long long)t * E_ + tid * 4);
        a4.x += v.x * a; a4.y += v.y * a; a4.z += v.z * a; a4.w += v.w * a;
    }
    *(float4*)(orow + 2 * E_ + tid * 4) = a4;
}

extern "C" void kernel_launch(void* const* d_in, const int* in_sizes, int n_in,
                              void* d_out, int out_size, void* d_ws, size_t ws_size,
                              hipStream_t stream) {
    const float* x       = (const float*)d_in[0];
    const int*   starts  = (const int*)d_in[1];
    const int*   lengths = (const int*)d_in[2];
    const int*   nspans  = (const int*)d_in[3];
    const float* Wa1 = (const float*)d_in[4];
    const float* ba1 = (const float*)d_in[5];
    const float* Wa2 = (const float*)d_in[6];
    const float* ba2 = (const float*)d_in[7];
    const float* Wa3 = (const float*)d_in[8];
    const float* ba3 = (const float*)d_in[9];
    const float* Ws1 = (const float*)d_in[10];
    const float* bs1 = (const float*)d_in[11];
    const float* Ws2 = (const float*)d_in[12];
    const float* bs2 = (const float*)d_in[13];
    const float* Ws3 = (const float*)d_in[14];
    const float* bs3 = (const float*)d_in[15];

    float* out        = (float*)d_out;                       // span_emb [B,S,3E]
    float* out_scores = out + (long long)B_ * S_ * 3 * E_;   // scores [B,S]

    // workspace layout (16B-aligned offsets)
    char* ws = (char*)d_ws;
    float*          attn = (float*)ws;                         // 131072 B
    __hip_bfloat16* Wt1a = (__hip_bfloat16*)(ws + 131072);     // 160*1024*2
    __hip_bfloat16* Wt2a = (__hip_bfloat16*)(ws + 458752);     // 160*160*2
    __hip_bfloat16* Wt1s = (__hip_bfloat16*)(ws + 509952);     // 160*3072*2
    __hip_bfloat16* Wt2s = (__hip_bfloat16*)(ws + 1492992);    // 160*160*2

    // 0) pre-transpose weights to bf16 [NPAD][K]
    transpose_w<E_,  E_ ><<<(NPAD * E_ ) / 256, 256, 0, stream>>>(Wa1, Wt1a);
    transpose_w<HID_,NPAD><<<(NPAD * NPAD) / 256, 256, 0, stream>>>(Wa2, Wt2a);
    transpose_w<GI_, GI_ ><<<(NPAD * GI_ ) / 256, 256, 0, stream>>>(Ws1, Wt1s);
    transpose_w<HID_,NPAD><<<(NPAD * NPAD) / 256, 256, 0, stream>>>(Ws2, Wt2s);

    // 1) attention score per token (32768 rows, 1024 blocks)
    mlp_mfma<E_><<<(B_ * T_) / MROWS, 256, 0, stream>>>
        (x, Wt1a, ba1, Wt2a, ba2, Wa3, ba3, attn);

    // 2) span embeddings (direct ragged sum; lengths < 24)
    span_kernel<<<B_ * S_, 256, 0, stream>>>(x, attn, starts, lengths, nspans, out);

    // 3) mention scores from span_emb (32000 rows, 1000 blocks)
    mlp_mfma<GI_><<<(B_ * S_) / MROWS, 256, 0, stream>>>
        (out, Wt1s, bs1, Wt2s, bs2, Ws3, bs3, out_scores);
}

// Round 8
// 350.026 us; speedup vs baseline: 1.7233x; 1.7233x over previous
//
#include <hip/hip_runtime.h>
#include <hip/hip_bf16.h>
#include <stdint.h>

#define B_   16
#define T_   2048
#define E_   1024
#define S_   2000
#define HID_ 150
#define GI_  3072

typedef __attribute__((ext_vector_type(8))) short short8;   // 8 bf16 (4 VGPRs)
typedef __attribute__((ext_vector_type(4))) float f32x4;

constexpr int NPAD  = 160;   // HID padded to 10 MFMA col-tiles
constexpr int LSTR  = 168;   // hl row stride (bf16): 336 B
constexpr int MROWS = 64;    // rows per MLP block (4 waves)

__device__ __forceinline__ void gload16(const void* gsrc, void* ldst) {
    __builtin_amdgcn_global_load_lds(
        (const __attribute__((address_space(1))) unsigned int*)gsrc,
        (__attribute__((address_space(3))) unsigned int*)ldst,
        16, 0, 0);   // 16B per lane, wave-uniform LDS base + lane*16
}

__device__ __forceinline__ short8 pack8(float4 a, float4 b) {
    union { __hip_bfloat162 h[4]; short8 s; } u;
    u.h[0] = __float22bfloat162_rn(make_float2(a.x, a.y));
    u.h[1] = __float22bfloat162_rn(make_float2(a.z, a.w));
    u.h[2] = __float22bfloat162_rn(make_float2(b.x, b.y));
    u.h[3] = __float22bfloat162_rn(make_float2(b.z, b.w));
    return u.s;
}

// W [K x 150] f32  ->  Wt [160][DSTK] bf16, zero-padded (n>=150 or k>=SRCK)
template<int SRCK, int DSTK>
__global__ __launch_bounds__(256)
void transpose_w(const float* __restrict__ src, __hip_bfloat16* __restrict__ dst) {
    int i = blockIdx.x * 256 + threadIdx.x;      // i = n*DSTK + k
    if (i >= NPAD * DSTK) return;
    int n = i / DSTK, k = i - n * DSTK;
    float v = (n < HID_ && k < SRCK) ? src[(long long)k * HID_ + n] : 0.f;
    dst[i] = __float2bfloat16(v);
}

// Full MLP: K1 -> 150 (relu) -> 150 (relu) -> 1, 64 rows/block, 4 waves.
// Stage 1: A(f32) and B(bf16) staged per 64-K chunk via global_load_lds DMA,
// 2-phase double buffer, one barrier per chunk. Source-swizzled (slot^row&7)
// with matching XOR on ds_read (rule #21: both sides, same involution).
template<int K1>
__global__ __launch_bounds__(256, 2)
void mlp_mfma(const float* __restrict__ xin,
              const __hip_bfloat16* __restrict__ Wt1, const float* __restrict__ b1,
              const __hip_bfloat16* __restrict__ Wt2, const float* __restrict__ b2,
              const float* __restrict__ W3, const float* __restrict__ b3,
              float* __restrict__ outp)
{
    constexpr int NC = K1 / 64;                       // 64-float K-chunks
    __shared__ __align__(16) float sA[2][64 * 64];            // 2 x 16 KB
    __shared__ __align__(16) __hip_bfloat16 sB[2][160 * 64];  // 2 x 20 KB

    const int tid  = threadIdx.x;
    const int lane = tid & 63;
    const int w    = tid >> 6;        // wave 0..3
    const int rg   = w >> 1;          // rows rg*32 + rt*16
    const int cg   = w & 1;           // cols cg*80
    const int lr   = lane & 15;
    const int hi   = lane >> 4;       // 0..3

    const long long row0 = (long long)blockIdx.x * MROWS;

    // ---- DMA staging of one 64-K chunk (per-lane global addr pre-swizzled) ----
    auto stageA = [&](int bi, int c) {
#pragma unroll
        for (int j = 0; j < 4; ++j) {                 // 4 calls x 1KB per wave
            const int row  = (w * 4 + j) * 4 + (lane >> 4);
            const int slot = (lane & 15) ^ (row & 7);
            gload16(xin + (row0 + row) * (long long)K1 + c * 64 + slot * 4,
                    &sA[bi][(w * 4 + j) * 256]);
        }
    };
    auto stageB = [&](int bi, int c) {
#pragma unroll
        for (int j = 0; j < 5; ++j) {                 // 5 calls x 1KB per wave
            const int nrow = (w * 5 + j) * 8 + (lane >> 3);
            const int slot = (lane & 7) ^ (nrow & 7);
            gload16(Wt1 + (long long)nrow * K1 + c * 64 + slot * 8,
                    &sB[bi][(w * 5 + j) * 512]);
        }
    };

    // ---------------- stage 1: K1 -> 160 (MFMA, 2-phase DMA pipeline) --------
    f32x4 acc[2][5];
#pragma unroll
    for (int rt = 0; rt < 2; ++rt)
#pragma unroll
        for (int nt = 0; nt < 5; ++nt) acc[rt][nt] = (f32x4){0.f, 0.f, 0.f, 0.f};

    stageA(0, 0);
    stageB(0, 0);

    for (int c = 0; c < NC; ++c) {
        __syncthreads();                  // vmcnt(0)+barrier: buf[c&1] ready
        if (c + 1 < NC) {                 // issue next chunk; flies during MFMA
            stageA((c + 1) & 1, c + 1);
            stageB((c + 1) & 1, c + 1);
        }
        const int bi = c & 1;
#pragma unroll
        for (int ks = 0; ks < 2; ++ks) {
            short8 bfr[5];
#pragma unroll
            for (int nt = 0; nt < 5; ++nt) {
                const int nrow = cg * 80 + nt * 16 + lr;
                const int slot = (ks * 4 + hi) ^ (nrow & 7);
                bfr[nt] = *(const short8*)&sB[bi][nrow * 64 + slot * 8];
            }
#pragma unroll
            for (int rt = 0; rt < 2; ++rt) {
                const int r  = rg * 32 + rt * 16 + lr;
                const int s0 = (ks * 8 + hi * 2) ^ (r & 7);
                const int s1 = (ks * 8 + hi * 2 + 1) ^ (r & 7);
                float4 a0 = *(const float4*)&sA[bi][r * 64 + s0 * 4];
                float4 a1 = *(const float4*)&sA[bi][r * 64 + s1 * 4];
                short8 afr = pack8(a0, a1);
#pragma unroll
                for (int nt = 0; nt < 5; ++nt)
                    acc[rt][nt] = __builtin_amdgcn_mfma_f32_16x16x32_bf16(
                        afr, bfr[nt], acc[rt][nt], 0, 0, 0);
            }
        }
    }
    __syncthreads();   // all stage-1 LDS reads done; sA region now reusable

    __hip_bfloat16* hl = (__hip_bfloat16*)&sA[0][0];   // 21.5 KB alias

    // bias + relu -> hl (bf16)
#pragma unroll
    for (int nt = 0; nt < 5; ++nt) {
        const int ch = cg * 80 + nt * 16 + lr;
        const float bb = (ch < HID_) ? b1[ch] : 0.f;
#pragma unroll
        for (int rt = 0; rt < 2; ++rt)
#pragma unroll
            for (int r4 = 0; r4 < 4; ++r4) {
                const int row = rg * 32 + rt * 16 + hi * 4 + r4;
                float h = acc[rt][nt][r4] + bb;
                hl[row * LSTR + ch] = __float2bfloat16(h > 0.f ? h : 0.f);
            }
    }
    __syncthreads();

    // ---------------- stage 2: 160 -> 160 (MFMA, K=160) ----------------
    f32x4 acc2[2][5];
#pragma unroll
    for (int rt = 0; rt < 2; ++rt)
#pragma unroll
        for (int nt = 0; nt < 5; ++nt) acc2[rt][nt] = (f32x4){0.f, 0.f, 0.f, 0.f};

#pragma unroll
    for (int ks = 0; ks < 5; ++ks) {
        const int k0 = ks * 32 + hi * 8;
        short8 bfr[5];
#pragma unroll
        for (int nt = 0; nt < 5; ++nt)
            bfr[nt] = *(const short8*)(Wt2 + (cg * 80 + nt * 16 + lr) * NPAD + k0);
#pragma unroll
        for (int rt = 0; rt < 2; ++rt) {
            short8 afr = *(const short8*)&hl[(rg * 32 + rt * 16 + lr) * LSTR + k0];
#pragma unroll
            for (int nt = 0; nt < 5; ++nt)
                acc2[rt][nt] = __builtin_amdgcn_mfma_f32_16x16x32_bf16(
                    afr, bfr[nt], acc2[rt][nt], 0, 0, 0);
        }
    }
    __syncthreads();   // stage-2 reads done before overwrite

    // bias + relu -> hl (h2)
#pragma unroll
    for (int nt = 0; nt < 5; ++nt) {
        const int ch = cg * 80 + nt * 16 + lr;
        const float bb = (ch < HID_) ? b2[ch] : 0.f;
#pragma unroll
        for (int rt = 0; rt < 2; ++rt)
#pragma unroll
            for (int r4 = 0; r4 < 4; ++r4) {
                const int row = rg * 32 + rt * 16 + hi * 4 + r4;
                float h = acc2[rt][nt][r4] + bb;
                hl[row * LSTR + ch] = __float2bfloat16(h > 0.f ? h : 0.f);
            }
    }
    __syncthreads();

    // ---------------- stage 3: 150 -> 1 (4 threads per row) ----------------
    {
        const int row = tid >> 2, quad = tid & 3;
        const int kb = quad * 38;
        const int ke = (kb + 38 > HID_) ? HID_ : kb + 38;
        float s = 0.f;
        for (int k = kb; k < ke; ++k)
            s += __bfloat162float(hl[row * LSTR + k]) * W3[k];
        s += __shfl_xor(s, 1);
        s += __shfl_xor(s, 2);
        if (quad == 0) outp[row0 + row] = s + b3[0];
    }
}

// span_emb = [x[start], x[end], sum_{t=start..end} x[t]*attn[t]]  (f32 out)
__global__ __launch_bounds__(256)
void span_kernel(const float* __restrict__ x, const float* __restrict__ attn,
                 const int* __restrict__ starts, const int* __restrict__ lengths,
                 const int* __restrict__ nspans, float* __restrict__ out)
{
    const int blk = blockIdx.x;        // b*S + s
    const int b = blk / S_;
    const int s = blk - b * S_;
    const int tid = threadIdx.x;       // each thread: 4 consecutive elements
    float* orow = out + (long long)blk * (3 * E_);

    if (s >= nspans[b]) {
        float4 z = make_float4(0.f, 0.f, 0.f, 0.f);
        *(float4*)(orow + tid * 4)          = z;
        *(float4*)(orow + E_ + tid * 4)     = z;
        *(float4*)(orow + 2 * E_ + tid * 4) = z;
        return;
    }
    const int st = starts[blk];
    const int en = st + lengths[blk];   // inclusive end index, < T
    const float* xb = x + (long long)b * T_ * E_;

    float4 vs = *(const float4*)(xb + (long long)st * E_ + tid * 4);
    float4 ve = *(const float4*)(xb + (long long)en * E_ + tid * 4);
    *(float4*)(orow + tid * 4)      = vs;   // bit-exact g_start
    *(float4*)(orow + E_ + tid * 4) = ve;   // bit-exact g_end

    float4 a4 = make_float4(0.f, 0.f, 0.f, 0.f);
    const float* ab = attn + b * T_;
    for (int t = st; t <= en; ++t) {
        float a = ab[t];
        float4 v = *(const float4*)(xb + (long long)t * E_ + tid * 4);
        a4.x += v.x * a; a4.y += v.y * a; a4.z += v.z * a; a4.w += v.w * a;
    }
    *(float4*)(orow + 2 * E_ + tid * 4) = a4;
}

extern "C" void kernel_launch(void* const* d_in, const int* in_sizes, int n_in,
                              void* d_out, int out_size, void* d_ws, size_t ws_size,
                              hipStream_t stream) {
    const float* x       = (const float*)d_in[0];
    const int*   starts  = (const int*)d_in[1];
    const int*   lengths = (const int*)d_in[2];
    const int*   nspans  = (const int*)d_in[3];
    const float* Wa1 = (const float*)d_in[4];
    const float* ba1 = (const float*)d_in[5];
    const float* Wa2 = (const float*)d_in[6];
    const float* ba2 = (const float*)d_in[7];
    const float* Wa3 = (const float*)d_in[8];
    const float* ba3 = (const float*)d_in[9];
    const float* Ws1 = (const float*)d_in[10];
    const float* bs1 = (const float*)d_in[11];
    const float* Ws2 = (const float*)d_in[12];
    const float* bs2 = (const float*)d_in[13];
    const float* Ws3 = (const float*)d_in[14];
    const float* bs3 = (const float*)d_in[15];

    float* out        = (float*)d_out;                       // span_emb [B,S,3E]
    float* out_scores = out + (long long)B_ * S_ * 3 * E_;   // scores [B,S]

    // workspace layout (16B-aligned offsets)
    char* ws = (char*)d_ws;
    float*          attn = (float*)ws;                         // 131072 B
    __hip_bfloat16* Wt1a = (__hip_bfloat16*)(ws + 131072);     // 160*1024*2
    __hip_bfloat16* Wt2a = (__hip_bfloat16*)(ws + 458752);     // 160*160*2
    __hip_bfloat16* Wt1s = (__hip_bfloat16*)(ws + 509952);     // 160*3072*2
    __hip_bfloat16* Wt2s = (__hip_bfloat16*)(ws + 1492992);    // 160*160*2

    // 0) pre-transpose weights to bf16 [NPAD][K]
    transpose_w<E_,  E_ ><<<(NPAD * E_ ) / 256, 256, 0, stream>>>(Wa1, Wt1a);
    transpose_w<HID_,NPAD><<<(NPAD * NPAD) / 256, 256, 0, stream>>>(Wa2, Wt2a);
    transpose_w<GI_, GI_ ><<<(NPAD * GI_ ) / 256, 256, 0, stream>>>(Ws1, Wt1s);
    transpose_w<HID_,NPAD><<<(NPAD * NPAD) / 256, 256, 0, stream>>>(Ws2, Wt2s);

    // 1) attention score per token (32768 rows, 512 blocks)
    mlp_mfma<E_><<<(B_ * T_) / MROWS, 256, 0, stream>>>
        (x, Wt1a, ba1, Wt2a, ba2, Wa3, ba3, attn);

    // 2) span embeddings (direct ragged sum; lengths < 24)
    span_kernel<<<B_ * S_, 256, 0, stream>>>(x, attn, starts, lengths, nspans, out);

    // 3) mention scores from span_emb (32000 rows, 500 blocks)
    mlp_mfma<GI_><<<(B_ * S_) / MROWS, 256, 0, stream>>>
        (out, Wt1s, bs1, Wt2s, bs2, Ws3, bs3, out_scores);
}

// Round 9
// 307.830 us; speedup vs baseline: 1.9595x; 1.1371x over previous
//
#include <hip/hip_runtime.h>
#include <hip/hip_bf16.h>

#define B_   16
#define T_   2048
#define E_   1024
#define S_   2000
#define HID_ 150
#define GI_  3072

typedef __attribute__((ext_vector_type(8))) short short8;   // 8 bf16 (4 VGPRs)
typedef __attribute__((ext_vector_type(4))) float f32x4;

constexpr int NPAD  = 160;   // HID padded to 10 MFMA col-tiles
constexpr int LSTR  = 168;   // hl row stride (bf16): 336 B
constexpr int MROWS = 64;    // rows per MLP block (4 waves)

__device__ __forceinline__ void gload16(const void* gsrc, void* ldst) {
    __builtin_amdgcn_global_load_lds(
        (const __attribute__((address_space(1))) unsigned int*)gsrc,
        (__attribute__((address_space(3))) unsigned int*)ldst,
        16, 0, 0);   // 16B per lane, wave-uniform LDS base + lane*16
}

__device__ __forceinline__ short8 pack8(float4 a, float4 b) {
    union { __hip_bfloat162 h[4]; short8 s; } u;
    u.h[0] = __float22bfloat162_rn(make_float2(a.x, a.y));
    u.h[1] = __float22bfloat162_rn(make_float2(a.z, a.w));
    u.h[2] = __float22bfloat162_rn(make_float2(b.x, b.y));
    u.h[3] = __float22bfloat162_rn(make_float2(b.z, b.w));
    return u.s;
}

__device__ __forceinline__ void store_bf16x4(__hip_bfloat16* p, float4 v) {
    union { __hip_bfloat162 h[2]; uint2 u; } cv;
    cv.h[0] = __float22bfloat162_rn(make_float2(v.x, v.y));
    cv.h[1] = __float22bfloat162_rn(make_float2(v.z, v.w));
    *reinterpret_cast<uint2*>(p) = cv.u;
}

// All four weight transposes (f32 [K][150] -> bf16 [160][K], zero-padded) in one launch.
__global__ __launch_bounds__(256)
void transpose_all(const float* __restrict__ Wa1, const float* __restrict__ Wa2,
                   const float* __restrict__ Ws1, const float* __restrict__ Ws2,
                   __hip_bfloat16* __restrict__ Wt1a, __hip_bfloat16* __restrict__ Wt2a,
                   __hip_bfloat16* __restrict__ Wt1s, __hip_bfloat16* __restrict__ Wt2s)
{
    const int s0 = 160 * 1024, s1 = 160 * 160, s2 = 160 * 3072, s3 = 160 * 160;
    int i = blockIdx.x * 256 + threadIdx.x;
    if (i < s0) {
        int n = i >> 10, k = i & 1023;
        Wt1a[i] = __float2bfloat16(n < HID_ ? Wa1[k * HID_ + n] : 0.f);
    } else if (i < s0 + s1) {
        int j = i - s0, n = j / 160, k = j - n * 160;
        Wt2a[j] = __float2bfloat16((n < HID_ && k < HID_) ? Wa2[k * HID_ + n] : 0.f);
    } else if (i < s0 + s1 + s2) {
        int j = i - s0 - s1, n = j / 3072, k = j - n * 3072;
        Wt1s[j] = __float2bfloat16(n < HID_ ? Ws1[k * HID_ + n] : 0.f);
    } else if (i < s0 + s1 + s2 + s3) {
        int j = i - s0 - s1 - s2, n = j / 160, k = j - n * 160;
        Wt2s[j] = __float2bfloat16((n < HID_ && k < HID_) ? Ws2[k * HID_ + n] : 0.f);
    }
}

// Full MLP: K1 -> 150 (relu) -> 150 (relu) -> 1, 64 rows/block, 4 waves.
// Stage 1: A (f32 or bf16) and B (bf16) staged per 64-K chunk via
// global_load_lds DMA, 2-phase double buffer, one barrier per chunk.
// Source-swizzled (slot ^ row&7) with matching XOR on the LDS read.
template<int K1, bool BF16A>
__global__ __launch_bounds__(256, 2)
void mlp_mfma(const void* __restrict__ xin_,
              const __hip_bfloat16* __restrict__ Wt1, const float* __restrict__ b1,
              const __hip_bfloat16* __restrict__ Wt2, const float* __restrict__ b2,
              const float* __restrict__ W3, const float* __restrict__ b3,
              float* __restrict__ outp)
{
    constexpr int NC  = K1 / 64;                      // 64-elem K-chunks
    constexpr int ACH = 64 * 64 * (BF16A ? 2 : 4);    // A chunk bytes
    constexpr int BCH = 160 * 64 * 2;                 // B chunk bytes
    __shared__ __align__(16) char smem[2 * ACH + 2 * BCH];

    const int tid  = threadIdx.x;
    const int lane = tid & 63;
    const int w    = tid >> 6;        // wave 0..3
    const int rg   = w >> 1;          // rows rg*32 + rt*16
    const int cg   = w & 1;           // cols cg*80
    const int lr   = lane & 15;
    const int hi   = lane >> 4;       // 0..3

    const long long row0 = (long long)blockIdx.x * MROWS;

    auto stageA = [&](int bi, int c) {
        char* dst = smem + bi * ACH;
        if constexpr (BF16A) {
            const __hip_bfloat16* xb = (const __hip_bfloat16*)xin_;
#pragma unroll
            for (int j = 0; j < 2; ++j) {             // 2 x 1KB per wave
                const int row  = (w * 2 + j) * 8 + (lane >> 3);
                const int slot = (lane & 7) ^ (row & 7);
                gload16(xb + (row0 + row) * (long long)K1 + c * 64 + slot * 8,
                        dst + (w * 2 + j) * 1024);
            }
        } else {
            const float* xf = (const float*)xin_;
#pragma unroll
            for (int j = 0; j < 4; ++j) {             // 4 x 1KB per wave
                const int row  = (w * 4 + j) * 4 + (lane >> 4);
                const int slot = (lane & 15) ^ (row & 7);
                gload16(xf + (row0 + row) * (long long)K1 + c * 64 + slot * 4,
                        dst + (w * 4 + j) * 1024);
            }
        }
    };
    auto stageB = [&](int bi, int c) {
        char* dst = smem + 2 * ACH + bi * BCH;
#pragma unroll
        for (int j = 0; j < 5; ++j) {                 // 5 x 1KB per wave
            const int nrow = (w * 5 + j) * 8 + (lane >> 3);
            const int slot = (lane & 7) ^ (nrow & 7);
            gload16(Wt1 + (long long)nrow * K1 + c * 64 + slot * 8,
                    dst + (w * 5 + j) * 1024);
        }
    };

    // ---------------- stage 1: K1 -> 160 (MFMA, 2-phase DMA pipeline) --------
    f32x4 acc[2][5];
#pragma unroll
    for (int rt = 0; rt < 2; ++rt)
#pragma unroll
        for (int nt = 0; nt < 5; ++nt) acc[rt][nt] = (f32x4){0.f, 0.f, 0.f, 0.f};

    stageA(0, 0);
    stageB(0, 0);

    for (int c = 0; c < NC; ++c) {
        __syncthreads();                  // buf[c&1] ready
        if (c + 1 < NC) {                 // next chunk flies during MFMA
            stageA((c + 1) & 1, c + 1);
            stageB((c + 1) & 1, c + 1);
        }
        const int bi = c & 1;
        const char* sA = smem + bi * ACH;
        const char* sB = smem + 2 * ACH + bi * BCH;
#pragma unroll
        for (int ks = 0; ks < 2; ++ks) {
            short8 bfr[5];
#pragma unroll
            for (int nt = 0; nt < 5; ++nt) {
                const int nrow = cg * 80 + nt * 16 + lr;
                const int slot = (ks * 4 + hi) ^ (nrow & 7);
                bfr[nt] = *(const short8*)(sB + nrow * 128 + slot * 16);
            }
#pragma unroll
            for (int rt = 0; rt < 2; ++rt) {
                const int r = rg * 32 + rt * 16 + lr;
                short8 afr;
                if constexpr (BF16A) {
                    const int slot = (ks * 4 + hi) ^ (r & 7);
                    afr = *(const short8*)(sA + r * 128 + slot * 16);
                } else {
                    const int s0i = (ks * 8 + hi * 2) ^ (r & 7);
                    const int s1i = (ks * 8 + hi * 2 + 1) ^ (r & 7);
                    float4 a0 = *(const float4*)(sA + r * 256 + s0i * 16);
                    float4 a1 = *(const float4*)(sA + r * 256 + s1i * 16);
                    afr = pack8(a0, a1);
                }
#pragma unroll
                for (int nt = 0; nt < 5; ++nt)
                    acc[rt][nt] = __builtin_amdgcn_mfma_f32_16x16x32_bf16(
                        afr, bfr[nt], acc[rt][nt], 0, 0, 0);
            }
        }
    }
    __syncthreads();   // all stage-1 LDS reads done; smem reusable

    __hip_bfloat16* hl = (__hip_bfloat16*)smem;   // 21.5 KB alias

    // bias + relu -> hl (bf16)
#pragma unroll
    for (int nt = 0; nt < 5; ++nt) {
        const int ch = cg * 80 + nt * 16 + lr;
        const float bb = (ch < HID_) ? b1[ch] : 0.f;
#pragma unroll
        for (int rt = 0; rt < 2; ++rt)
#pragma unroll
            for (int r4 = 0; r4 < 4; ++r4) {
                const int row = rg * 32 + rt * 16 + hi * 4 + r4;
                float h = acc[rt][nt][r4] + bb;
                hl[row * LSTR + ch] = __float2bfloat16(h > 0.f ? h : 0.f);
            }
    }
    __syncthreads();

    // ---------------- stage 2: 160 -> 160 (MFMA, K=160) ----------------
    f32x4 acc2[2][5];
#pragma unroll
    for (int rt = 0; rt < 2; ++rt)
#pragma unroll
        for (int nt = 0; nt < 5; ++nt) acc2[rt][nt] = (f32x4){0.f, 0.f, 0.f, 0.f};

#pragma unroll
    for (int ks = 0; ks < 5; ++ks) {
        const int k0 = ks * 32 + hi * 8;
        short8 bfr[5];
#pragma unroll
        for (int nt = 0; nt < 5; ++nt)
            bfr[nt] = *(const short8*)(Wt2 + (cg * 80 + nt * 16 + lr) * NPAD + k0);
#pragma unroll
        for (int rt = 0; rt < 2; ++rt) {
            short8 afr = *(const short8*)&hl[(rg * 32 + rt * 16 + lr) * LSTR + k0];
#pragma unroll
            for (int nt = 0; nt < 5; ++nt)
                acc2[rt][nt] = __builtin_amdgcn_mfma_f32_16x16x32_bf16(
                    afr, bfr[nt], acc2[rt][nt], 0, 0, 0);
        }
    }
    __syncthreads();

    // bias + relu -> hl (h2)
#pragma unroll
    for (int nt = 0; nt < 5; ++nt) {
        const int ch = cg * 80 + nt * 16 + lr;
        const float bb = (ch < HID_) ? b2[ch] : 0.f;
#pragma unroll
        for (int rt = 0; rt < 2; ++rt)
#pragma unroll
            for (int r4 = 0; r4 < 4; ++r4) {
                const int row = rg * 32 + rt * 16 + hi * 4 + r4;
                float h = acc2[rt][nt][r4] + bb;
                hl[row * LSTR + ch] = __float2bfloat16(h > 0.f ? h : 0.f);
            }
    }
    __syncthreads();

    // ---------------- stage 3: 150 -> 1 (4 threads per row) ----------------
    {
        const int row = tid >> 2, quad = tid & 3;
        const int kb = quad * 38;
        const int ke = (kb + 38 > HID_) ? HID_ : kb + 38;
        float s = 0.f;
        for (int k = kb; k < ke; ++k)
            s += __bfloat162float(hl[row * LSTR + k]) * W3[k];
        s += __shfl_xor(s, 1);
        s += __shfl_xor(s, 2);
        if (quad == 0) outp[row0 + row] = s + b3[0];
    }
}

// span_emb = [x[start], x[end], sum_{t} attn[t]*x[t]]: f32 to d_out (exact
// gathers) + bf16 shadow to d_ws (consumed by the score MLP; fits L3).
__global__ __launch_bounds__(256)
void span_kernel(const float* __restrict__ x, const float* __restrict__ attn,
                 const int* __restrict__ starts, const int* __restrict__ lengths,
                 const int* __restrict__ nspans, float* __restrict__ out,
                 __hip_bfloat16* __restrict__ shadow)
{
    const int blk = blockIdx.x;        // b*S + s
    const int b = blk / S_;
    const int s = blk - b * S_;
    const int tid = threadIdx.x;       // each thread: 4 consecutive elements
    float* orow = out + (long long)blk * (3 * E_);
    __hip_bfloat16* srow = shadow + (long long)blk * (3 * E_);

    if (s >= nspans[b]) {
        float4 z = make_float4(0.f, 0.f, 0.f, 0.f);
        *(float4*)(orow + tid * 4)          = z;
        *(float4*)(orow + E_ + tid * 4)     = z;
        *(float4*)(orow + 2 * E_ + tid * 4) = z;
        uint2 z2 = make_uint2(0u, 0u);
        *(uint2*)(srow + tid * 4)          = z2;
        *(uint2*)(srow + E_ + tid * 4)     = z2;
        *(uint2*)(srow + 2 * E_ + tid * 4) = z2;
        return;
    }
    const int st = starts[blk];
    const int en = st + lengths[blk];   // inclusive end index, < T
    const float* xb = x + (long long)b * T_ * E_;

    float4 vs = *(const float4*)(xb + (long long)st * E_ + tid * 4);
    float4 ve = *(const float4*)(xb + (long long)en * E_ + tid * 4);
    *(float4*)(orow + tid * 4)      = vs;   // bit-exact g_start
    *(float4*)(orow + E_ + tid * 4) = ve;   // bit-exact g_end
    store_bf16x4(srow + tid * 4, vs);
    store_bf16x4(srow + E_ + tid * 4, ve);

    // 2-way unrolled weighted sum (dual accumulators -> 2x in-flight reads)
    float4 a0 = make_float4(0.f, 0.f, 0.f, 0.f);
    float4 a1 = make_float4(0.f, 0.f, 0.f, 0.f);
    const float* ab = attn + b * T_;
    int t = st;
    for (; t + 1 <= en; t += 2) {
        float w0 = ab[t], w1 = ab[t + 1];
        float4 v0 = *(const float4*)(xb + (long long)t * E_ + tid * 4);
        float4 v1 = *(const float4*)(xb + (long long)(t + 1) * E_ + tid * 4);
        a0.x += v0.x * w0; a0.y += v0.y * w0; a0.z += v0.z * w0; a0.w += v0.w * w0;
        a1.x += v1.x * w1; a1.y += v1.y * w1; a1.z += v1.z * w1; a1.w += v1.w * w1;
    }
    if (t <= en) {
        float w0 = ab[t];
        float4 v0 = *(const float4*)(xb + (long long)t * E_ + tid * 4);
        a0.x += v0.x * w0; a0.y += v0.y * w0; a0.z += v0.z * w0; a0.w += v0.w * w0;
    }
    float4 a4 = make_float4(a0.x + a1.x, a0.y + a1.y, a0.z + a1.z, a0.w + a1.w);
    *(float4*)(orow + 2 * E_ + tid * 4) = a4;
    store_bf16x4(srow + 2 * E_ + tid * 4, a4);
}

extern "C" void kernel_launch(void* const* d_in, const int* in_sizes, int n_in,
                              void* d_out, int out_size, void* d_ws, size_t ws_size,
                              hipStream_t stream) {
    const float* x       = (const float*)d_in[0];
    const int*   starts  = (const int*)d_in[1];
    const int*   lengths = (const int*)d_in[2];
    const int*   nspans  = (const int*)d_in[3];
    const float* Wa1 = (const float*)d_in[4];
    const float* ba1 = (const float*)d_in[5];
    const float* Wa2 = (const float*)d_in[6];
    const float* ba2 = (const float*)d_in[7];
    const float* Wa3 = (const float*)d_in[8];
    const float* ba3 = (const float*)d_in[9];
    const float* Ws1 = (const float*)d_in[10];
    const float* bs1 = (const float*)d_in[11];
    const float* Ws2 = (const float*)d_in[12];
    const float* bs2 = (const float*)d_in[13];
    const float* Ws3 = (const float*)d_in[14];
    const float* bs3 = (const float*)d_in[15];

    float* out        = (float*)d_out;                       // span_emb [B,S,3E]
    float* out_scores = out + (long long)B_ * S_ * 3 * E_;   // scores [B,S]

    // workspace layout (16B-aligned offsets)
    char* ws = (char*)d_ws;
    float*          attn   = (float*)ws;                       // 131072 B
    __hip_bfloat16* Wt1a   = (__hip_bfloat16*)(ws + 131072);   // 160*1024*2
    __hip_bfloat16* Wt2a   = (__hip_bfloat16*)(ws + 458752);   // 160*160*2
    __hip_bfloat16* Wt1s   = (__hip_bfloat16*)(ws + 509952);   // 160*3072*2
    __hip_bfloat16* Wt2s   = (__hip_bfloat16*)(ws + 1492992);  // 160*160*2
    __hip_bfloat16* shadow = (__hip_bfloat16*)(ws + 1544192);  // 32000*3072*2 = 196.6 MB

    // 0) all weight transposes (one launch)
    transpose_all<<<2760, 256, 0, stream>>>(Wa1, Wa2, Ws1, Ws2,
                                            Wt1a, Wt2a, Wt1s, Wt2s);

    // 1) attention score per token (32768 rows, 512 blocks, f32 A)
    mlp_mfma<E_, false><<<(B_ * T_) / MROWS, 256, 0, stream>>>
        (x, Wt1a, ba1, Wt2a, ba2, Wa3, ba3, attn);

    // 2) span embeddings: f32 -> d_out, bf16 shadow -> ws
    span_kernel<<<B_ * S_, 256, 0, stream>>>(x, attn, starts, lengths, nspans,
                                             out, shadow);

    // 3) mention scores from bf16 shadow (32000 rows, 500 blocks, bf16 A)
    mlp_mfma<GI_, true><<<(B_ * S_) / MROWS, 256, 0, stream>>>
        (shadow, Wt1s, bs1, Wt2s, bs2, Ws3, bs3, out_scores);
}

// Round 10
// 269.252 us; speedup vs baseline: 2.2403x; 1.1433x over previous
//
#include <hip/hip_runtime.h>
#include <hip/hip_bf16.h>

#define B_   16
#define T_   2048
#define E_   1024
#define S_   2000
#define HID_ 150
#define GI_  3072

typedef __attribute__((ext_vector_type(8))) short short8;   // 8 bf16 (4 VGPRs)
typedef __attribute__((ext_vector_type(4))) float f32x4;

constexpr int NPAD  = 160;   // HID padded to 10 MFMA col-tiles
constexpr int LSTR  = 168;   // hl row stride (bf16): 336 B
constexpr int MROWS = 64;    // rows per MLP block

__device__ __forceinline__ void gload16(const void* gsrc, void* ldst) {
    __builtin_amdgcn_global_load_lds(
        (const __attribute__((address_space(1))) unsigned int*)gsrc,
        (__attribute__((address_space(3))) unsigned int*)ldst,
        16, 0, 0);   // 16B/lane, wave-uniform LDS base + lane*16
}

__device__ __forceinline__ short8 pack8(float4 a, float4 b) {
    union { __hip_bfloat162 h[4]; short8 s; } u;
    u.h[0] = __float22bfloat162_rn(make_float2(a.x, a.y));
    u.h[1] = __float22bfloat162_rn(make_float2(a.z, a.w));
    u.h[2] = __float22bfloat162_rn(make_float2(b.x, b.y));
    u.h[3] = __float22bfloat162_rn(make_float2(b.z, b.w));
    return u.s;
}

// All four weight transposes (f32 [K][150] -> bf16 [160][K], zero-padded).
__global__ __launch_bounds__(256)
void transpose_all(const float* __restrict__ Wa1, const float* __restrict__ Wa2,
                   const float* __restrict__ Ws1, const float* __restrict__ Ws2,
                   __hip_bfloat16* __restrict__ Wt1a, __hip_bfloat16* __restrict__ Wt2a,
                   __hip_bfloat16* __restrict__ Wt1s, __hip_bfloat16* __restrict__ Wt2s)
{
    const int s0 = 160 * 1024, s1 = 160 * 160, s2 = 160 * 3072, s3 = 160 * 160;
    int i = blockIdx.x * 256 + threadIdx.x;
    if (i < s0) {
        int n = i >> 10, k = i & 1023;
        Wt1a[i] = __float2bfloat16(n < HID_ ? Wa1[k * HID_ + n] : 0.f);
    } else if (i < s0 + s1) {
        int j = i - s0, n = j / 160, k = j - n * 160;
        Wt2a[j] = __float2bfloat16((n < HID_ && k < HID_) ? Wa2[k * HID_ + n] : 0.f);
    } else if (i < s0 + s1 + s2) {
        int j = i - s0 - s1, n = j / 3072, k = j - n * 3072;
        Wt1s[j] = __float2bfloat16(n < HID_ ? Ws1[k * HID_ + n] : 0.f);
    } else if (i < s0 + s1 + s2 + s3) {
        int j = i - s0 - s1 - s2, n = j / 160, k = j - n * 160;
        Wt2s[j] = __float2bfloat16((n < HID_ && k < HID_) ? Ws2[k * HID_ + n] : 0.f);
    }
}

// attn MLP: 1024 -> 150 relu -> 150 relu -> 1, 64 rows/block, 4 waves.
// A(f32)+B(bf16) DMA-staged per 64-K chunk, 2-phase dbuf (R8 structure).
template<int K1>
__global__ __launch_bounds__(256, 2)
void mlp_mfma(const float* __restrict__ xin,
              const __hip_bfloat16* __restrict__ Wt1, const float* __restrict__ b1,
              const __hip_bfloat16* __restrict__ Wt2, const float* __restrict__ b2,
              const float* __restrict__ W3, const float* __restrict__ b3,
              float* __restrict__ outp)
{
    constexpr int NC  = K1 / 64;
    constexpr int ACH = 64 * 64 * 4;
    constexpr int BCH = 160 * 64 * 2;
    __shared__ __align__(16) char smem[2 * ACH + 2 * BCH];

    const int tid  = threadIdx.x;
    const int lane = tid & 63;
    const int w    = tid >> 6;
    const int rg   = w >> 1;
    const int cg   = w & 1;
    const int lr   = lane & 15;
    const int hi   = lane >> 4;

    const long long row0 = (long long)blockIdx.x * MROWS;

    auto stageA = [&](int bi, int c) {
        char* dst = smem + bi * ACH;
#pragma unroll
        for (int j = 0; j < 4; ++j) {
            const int row  = (w * 4 + j) * 4 + (lane >> 4);
            const int slot = (lane & 15) ^ (row & 7);
            gload16(xin + (row0 + row) * (long long)K1 + c * 64 + slot * 4,
                    dst + (w * 4 + j) * 1024);
        }
    };
    auto stageB = [&](int bi, int c) {
        char* dst = smem + 2 * ACH + bi * BCH;
#pragma unroll
        for (int j = 0; j < 5; ++j) {
            const int nrow = (w * 5 + j) * 8 + (lane >> 3);
            const int slot = (lane & 7) ^ (nrow & 7);
            gload16(Wt1 + (long long)nrow * K1 + c * 64 + slot * 8,
                    dst + (w * 5 + j) * 1024);
        }
    };

    f32x4 acc[2][5];
#pragma unroll
    for (int rt = 0; rt < 2; ++rt)
#pragma unroll
        for (int nt = 0; nt < 5; ++nt) acc[rt][nt] = (f32x4){0.f, 0.f, 0.f, 0.f};

    stageA(0, 0);
    stageB(0, 0);

    for (int c = 0; c < NC; ++c) {
        __syncthreads();
        if (c + 1 < NC) { stageA((c + 1) & 1, c + 1); stageB((c + 1) & 1, c + 1); }
        const int bi = c & 1;
        const char* sA = smem + bi * ACH;
        const char* sB = smem + 2 * ACH + bi * BCH;
#pragma unroll
        for (int ks = 0; ks < 2; ++ks) {
            short8 bfr[5];
#pragma unroll
            for (int nt = 0; nt < 5; ++nt) {
                const int nrow = cg * 80 + nt * 16 + lr;
                const int slot = (ks * 4 + hi) ^ (nrow & 7);
                bfr[nt] = *(const short8*)(sB + nrow * 128 + slot * 16);
            }
#pragma unroll
            for (int rt = 0; rt < 2; ++rt) {
                const int r = rg * 32 + rt * 16 + lr;
                const int s0i = (ks * 8 + hi * 2) ^ (r & 7);
                const int s1i = (ks * 8 + hi * 2 + 1) ^ (r & 7);
                float4 a0 = *(const float4*)(sA + r * 256 + s0i * 16);
                float4 a1 = *(const float4*)(sA + r * 256 + s1i * 16);
                short8 afr = pack8(a0, a1);
#pragma unroll
                for (int nt = 0; nt < 5; ++nt)
                    acc[rt][nt] = __builtin_amdgcn_mfma_f32_16x16x32_bf16(
                        afr, bfr[nt], acc[rt][nt], 0, 0, 0);
            }
        }
    }
    __syncthreads();

    __hip_bfloat16* hl = (__hip_bfloat16*)smem;

#pragma unroll
    for (int nt = 0; nt < 5; ++nt) {
        const int ch = cg * 80 + nt * 16 + lr;
        const float bb = (ch < HID_) ? b1[ch] : 0.f;
#pragma unroll
        for (int rt = 0; rt < 2; ++rt)
#pragma unroll
            for (int r4 = 0; r4 < 4; ++r4) {
                const int row = rg * 32 + rt * 16 + hi * 4 + r4;
                float h = acc[rt][nt][r4] + bb;
                hl[row * LSTR + ch] = __float2bfloat16(h > 0.f ? h : 0.f);
            }
    }
    __syncthreads();

    f32x4 acc2[2][5];
#pragma unroll
    for (int rt = 0; rt < 2; ++rt)
#pragma unroll
        for (int nt = 0; nt < 5; ++nt) acc2[rt][nt] = (f32x4){0.f, 0.f, 0.f, 0.f};

#pragma unroll
    for (int ks = 0; ks < 5; ++ks) {
        const int k0 = ks * 32 + hi * 8;
        short8 bfr[5];
#pragma unroll
        for (int nt = 0; nt < 5; ++nt)
            bfr[nt] = *(const short8*)(Wt2 + (cg * 80 + nt * 16 + lr) * NPAD + k0);
#pragma unroll
        for (int rt = 0; rt < 2; ++rt) {
            short8 afr = *(const short8*)&hl[(rg * 32 + rt * 16 + lr) * LSTR + k0];
#pragma unroll
            for (int nt = 0; nt < 5; ++nt)
                acc2[rt][nt] = __builtin_amdgcn_mfma_f32_16x16x32_bf16(
                    afr, bfr[nt], acc2[rt][nt], 0, 0, 0);
        }
    }
    __syncthreads();

#pragma unroll
    for (int nt = 0; nt < 5; ++nt) {
        const int ch = cg * 80 + nt * 16 + lr;
        const float bb = (ch < HID_) ? b2[ch] : 0.f;
#pragma unroll
        for (int rt = 0; rt < 2; ++rt)
#pragma unroll
            for (int r4 = 0; r4 < 4; ++r4) {
                const int row = rg * 32 + rt * 16 + hi * 4 + r4;
                float h = acc2[rt][nt][r4] + bb;
                hl[row * LSTR + ch] = __float2bfloat16(h > 0.f ? h : 0.f);
            }
    }
    __syncthreads();

    {
        const int row = tid >> 2, quad = tid & 3;
        const int kb = quad * 38;
        const int ke = (kb + 38 > HID_) ? HID_ : kb + 38;
        float s = 0.f;
        for (int k = kb; k < ke; ++k)
            s += __bfloat162float(hl[row * LSTR + k]) * W3[k];
        s += __shfl_xor(s, 1);
        s += __shfl_xor(s, 2);
        if (quad == 0) outp[row0 + row] = s + b3[0];
    }
}

// Fused span construction + score MLP. 64 spans/block, 512 threads (8 waves).
// Per 64-col chunk: construct A (gathers / ragged sum) -> f32 to d_out +
// bf16 (XOR-swizzled) to LDS; B DMA-staged; MFMA consumes; 2-phase dbuf.
__global__ __launch_bounds__(512, 4)
void span_score(const float* __restrict__ x, const float* __restrict__ attn,
                const int* __restrict__ starts, const int* __restrict__ lengths,
                const int* __restrict__ nspans,
                const __hip_bfloat16* __restrict__ Wt1, const float* __restrict__ b1,
                const __hip_bfloat16* __restrict__ Wt2, const float* __restrict__ b2,
                const float* __restrict__ W3, const float* __restrict__ b3,
                float* __restrict__ spanout, float* __restrict__ scoreout)
{
    // layout: sA dbuf 2x8KB @0 ; sB dbuf 2x20KB @16384 ; meta @57344
    __shared__ __align__(16) char smem[58112];
    int* stL = (int*)(smem + 57344);
    int* enL = (int*)(smem + 57600);
    int* bL  = (int*)(smem + 57856);

    const int tid  = threadIdx.x;
    const int lane = tid & 63;
    const int w    = tid >> 6;     // 0..7
    const int rg   = w >> 1;       // 0..3 : rows rg*16..+16
    const int cg   = w & 1;        // cols cg*80..+80
    const int lr   = lane & 15;
    const int hi   = lane >> 4;

    // bijective XCD-aware swizzle over 500 blocks (q=62, r=4)
    int bid = blockIdx.x;
    {
        const int qq = 500 / 8, rr = 500 % 8;
        const int xcd = bid % 8, i = bid / 8;
        bid = (xcd < rr ? xcd * (qq + 1) : rr * (qq + 1) + (xcd - rr) * qq) + i;
    }
    const int span0 = bid * 64;

    if (tid < 64) {
        const int sp = span0 + tid;
        const int b  = sp / S_;
        const int s  = sp - b * S_;
        const bool val = s < nspans[b];
        const int st = val ? starts[sp] : 0;
        stL[tid] = st;
        enL[tid] = val ? (st + lengths[sp]) : -1;
        bL[tid]  = b;
    }
    __syncthreads();

    const int r    = tid >> 3;     // constructor row 0..63
    const int q    = tid & 7;      // 8 floats per thread
    const int st_r = stL[r];
    const int en_r = enL[r];
    const long long sp_r = span0 + r;
    const float* xb = x + (long long)bL[r] * T_ * E_;
    const float* ab = attn + bL[r] * T_;

    auto constructA = [&](int bi, int c) {
        float4 v0, v1;
        if (c < 32) {
            if (en_r >= st_r) {
                const int srow = (c < 16) ? st_r : en_r;
                const float* p = xb + (long long)srow * E_ + (c & 15) * 64 + q * 8;
                v0 = *(const float4*)p;
                v1 = *(const float4*)(p + 4);
            } else {
                v0 = make_float4(0.f, 0.f, 0.f, 0.f);
                v1 = make_float4(0.f, 0.f, 0.f, 0.f);
            }
        } else {
            const int cl = (c - 32) * 64 + q * 8;
            float4 s0 = make_float4(0.f,0.f,0.f,0.f), s1 = s0, s2 = s0, s3 = s0;
            int t = st_r;
            for (; t + 1 <= en_r; t += 2) {
                const float a0 = ab[t], a1 = ab[t + 1];
                const float* p0 = xb + (long long)t * E_ + cl;
                const float4 u0 = *(const float4*)p0;
                const float4 u1 = *(const float4*)(p0 + 4);
                const float4 z0 = *(const float4*)(p0 + E_);
                const float4 z1 = *(const float4*)(p0 + E_ + 4);
                s0.x += u0.x*a0; s0.y += u0.y*a0; s0.z += u0.z*a0; s0.w += u0.w*a0;
                s1.x += u1.x*a0; s1.y += u1.y*a0; s1.z += u1.z*a0; s1.w += u1.w*a0;
                s2.x += z0.x*a1; s2.y += z0.y*a1; s2.z += z0.z*a1; s2.w += z0.w*a1;
                s3.x += z1.x*a1; s3.y += z1.y*a1; s3.z += z1.z*a1; s3.w += z1.w*a1;
            }
            if (t <= en_r) {
                const float a0 = ab[t];
                const float* p0 = xb + (long long)t * E_ + cl;
                const float4 u0 = *(const float4*)p0;
                const float4 u1 = *(const float4*)(p0 + 4);
                s0.x += u0.x*a0; s0.y += u0.y*a0; s0.z += u0.z*a0; s0.w += u0.w*a0;
                s1.x += u1.x*a0; s1.y += u1.y*a0; s1.z += u1.z*a0; s1.w += u1.w*a0;
            }
            v0 = make_float4(s0.x+s2.x, s0.y+s2.y, s0.z+s2.z, s0.w+s2.w);
            v1 = make_float4(s1.x+s3.x, s1.y+s3.y, s1.z+s3.z, s1.w+s3.w);
        }
        float* orow = spanout + sp_r * (3 * E_) + c * 64 + q * 8;
        *(float4*)orow       = v0;
        *(float4*)(orow + 4) = v1;
        *(short8*)(smem + bi * 8192 + r * 128 + ((q ^ (r & 7)) * 16)) = pack8(v0, v1);
    };

    auto stageB = [&](int bi, int c) {
        char* dst = smem + 16384 + bi * 20480;
#pragma unroll
        for (int j = 0; j < 3; ++j) {
            const int idx = w * 3 + j;      // 20 x 1KB pieces over 8 waves
            if (idx < 20) {
                const int nrow = idx * 8 + (lane >> 3);
                const int slot = (lane & 7) ^ (nrow & 7);
                gload16(Wt1 + (long long)nrow * GI_ + c * 64 + slot * 8,
                        dst + idx * 1024);
            }
        }
    };

    // ---------------- stage 1: 3072 -> 160 ----------------
    f32x4 acc[5];
#pragma unroll
    for (int nt = 0; nt < 5; ++nt) acc[nt] = (f32x4){0.f, 0.f, 0.f, 0.f};

    constructA(0, 0);
    stageB(0, 0);

    for (int c = 0; c < 48; ++c) {
        __syncthreads();                 // A[c],B[c] ready; buf^1 reads done
        if (c + 1 < 48) stageB((c + 1) & 1, c + 1);
        const int bi = c & 1;
        const char* sAc = smem + bi * 8192;
        const char* sBc = smem + 16384 + bi * 20480;
#pragma unroll
        for (int ks = 0; ks < 2; ++ks) {
            short8 bfr[5];
#pragma unroll
            for (int nt = 0; nt < 5; ++nt) {
                const int nrow = cg * 80 + nt * 16 + lr;
                const int slot = (ks * 4 + hi) ^ (nrow & 7);
                bfr[nt] = *(const short8*)(sBc + nrow * 128 + slot * 16);
            }
            const int r2 = rg * 16 + lr;
            const int sl = (ks * 4 + hi) ^ (r2 & 7);
            short8 afr = *(const short8*)(sAc + r2 * 128 + sl * 16);
#pragma unroll
            for (int nt = 0; nt < 5; ++nt)
                acc[nt] = __builtin_amdgcn_mfma_f32_16x16x32_bf16(
                    afr, bfr[nt], acc[nt], 0, 0, 0);
        }
        if (c + 1 < 48) constructA((c + 1) & 1, c + 1);
    }
    __syncthreads();   // stage-1 LDS reads done; smem reusable

    __hip_bfloat16* hl = (__hip_bfloat16*)smem;   // 21.5 KB alias

#pragma unroll
    for (int nt = 0; nt < 5; ++nt) {
        const int ch = cg * 80 + nt * 16 + lr;
        const float bb = (ch < HID_) ? b1[ch] : 0.f;
#pragma unroll
        for (int r4 = 0; r4 < 4; ++r4) {
            const int row = rg * 16 + hi * 4 + r4;
            float h = acc[nt][r4] + bb;
            hl[row * LSTR + ch] = __float2bfloat16(h > 0.f ? h : 0.f);
        }
    }
    __syncthreads();

    // ---------------- stage 2: 160 -> 160 ----------------
    f32x4 acc2[5];
#pragma unroll
    for (int nt = 0; nt < 5; ++nt) acc2[nt] = (f32x4){0.f, 0.f, 0.f, 0.f};

#pragma unroll
    for (int ks = 0; ks < 5; ++ks) {
        const int k0 = ks * 32 + hi * 8;
        short8 bfr[5];
#pragma unroll
        for (int nt = 0; nt < 5; ++nt)
            bfr[nt] = *(const short8*)(Wt2 + (cg * 80 + nt * 16 + lr) * NPAD + k0);
        short8 afr = *(const short8*)&hl[(rg * 16 + lr) * LSTR + k0];
#pragma unroll
        for (int nt = 0; nt < 5; ++nt)
            acc2[nt] = __builtin_amdgcn_mfma_f32_16x16x32_bf16(
                afr, bfr[nt], acc2[nt], 0, 0, 0);
    }
    __syncthreads();

#pragma unroll
    for (int nt = 0; nt < 5; ++nt) {
        const int ch = cg * 80 + nt * 16 + lr;
        const float bb = (ch < HID_) ? b2[ch] : 0.f;
#pragma unroll
        for (int r4 = 0; r4 < 4; ++r4) {
            const int row = rg * 16 + hi * 4 + r4;
            float h = acc2[nt][r4] + bb;
            hl[row * LSTR + ch] = __float2bfloat16(h > 0.f ? h : 0.f);
        }
    }
    __syncthreads();

    // ---------------- stage 3: 150 -> 1 (8 threads/row) ----------------
    {
        const int row = tid >> 3, oct = tid & 7;
        const int kb = oct * 19;
        const int ke = (kb + 19 > HID_) ? HID_ : kb + 19;
        float s = 0.f;
        for (int k = kb; k < ke; ++k)
            s += __bfloat162float(hl[row * LSTR + k]) * W3[k];
        s += __shfl_xor(s, 1);
        s += __shfl_xor(s, 2);
        s += __shfl_xor(s, 4);
        if (oct == 0) scoreout[span0 + row] = s + b3[0];
    }
}

extern "C" void kernel_launch(void* const* d_in, const int* in_sizes, int n_in,
                              void* d_out, int out_size, void* d_ws, size_t ws_size,
                              hipStream_t stream) {
    const float* x       = (const float*)d_in[0];
    const int*   starts  = (const int*)d_in[1];
    const int*   lengths = (const int*)d_in[2];
    const int*   nspans  = (const int*)d_in[3];
    const float* Wa1 = (const float*)d_in[4];
    const float* ba1 = (const float*)d_in[5];
    const float* Wa2 = (const float*)d_in[6];
    const float* ba2 = (const float*)d_in[7];
    const float* Wa3 = (const float*)d_in[8];
    const float* ba3 = (const float*)d_in[9];
    const float* Ws1 = (const float*)d_in[10];
    const float* bs1 = (const float*)d_in[11];
    const float* Ws2 = (const float*)d_in[12];
    const float* bs2 = (const float*)d_in[13];
    const float* Ws3 = (const float*)d_in[14];
    const float* bs3 = (const float*)d_in[15];

    float* out        = (float*)d_out;                       // span_emb [B,S,3E]
    float* out_scores = out + (long long)B_ * S_ * 3 * E_;   // scores [B,S]

    char* ws = (char*)d_ws;
    float*          attn = (float*)ws;                       // 131072 B
    __hip_bfloat16* Wt1a = (__hip_bfloat16*)(ws + 131072);   // 160*1024*2
    __hip_bfloat16* Wt2a = (__hip_bfloat16*)(ws + 458752);   // 160*160*2
    __hip_bfloat16* Wt1s = (__hip_bfloat16*)(ws + 509952);   // 160*3072*2
    __hip_bfloat16* Wt2s = (__hip_bfloat16*)(ws + 1492992);  // 160*160*2

    // 0) weight transposes
    transpose_all<<<2760, 256, 0, stream>>>(Wa1, Wa2, Ws1, Ws2,
                                            Wt1a, Wt2a, Wt1s, Wt2s);

    // 1) attention score per token (32768 rows, 512 blocks)
    mlp_mfma<E_><<<(B_ * T_) / MROWS, 256, 0, stream>>>
        (x, Wt1a, ba1, Wt2a, ba2, Wa3, ba3, attn);

    // 2) fused span construction + mention-score MLP (500 blocks)
    span_score<<<500, 512, 0, stream>>>
        (x, attn, starts, lengths, nspans,
         Wt1s, bs1, Wt2s, bs2, Ws3, bs3, out, out_scores);
}